// Round 4
// baseline (1535.896 us; speedup 1.0000x reference)
//
#include <hip/hip_runtime.h>
#include <math.h>

#define NROWS 65536
#define KEMB  2048
#define DIM   64
#define DECAYF 0.99f
#define OMDF   0.01f
#define EPSF   1e-5f

// ---- ws layout (units of 4 bytes) ----
#define WS_DW    0         // 131072 floats (dw, fully written by k2)
#define WS_CNT   131072    // 2048 uints   (counts, fully written by k2)
#define WS_LOSS  133120    // 1 float      (zeroed by k0)
#define WS_ESQ   133632    // 2048 floats  (e_sq)
#define WS_SCALE 135680    // 2048 floats  (0.01/cs', K3->K4)
#define WS_IDX   137728    // 65536 ints   (argmin indices)

// ---- out layout (floats) ----
#define OUT_Q    0
#define OUT_ENC  4194304          // 65536*64
#define OUT_LOSS 138412032        // + 65536*2048
#define OUT_PERP 138412033
#define OUT_NE   138412034        // new_embedding; x_sq scratch k0->k1, overwritten by k4
#define OUT_NCS  138543106        // + 2048*64

typedef float f32x4 __attribute__((ext_vector_type(4)));

// K0: e_sq, x_sq (4-partial rounding), zero loss
__global__ __launch_bounds__(256) void k0_prep(const float* __restrict__ x,
                                               const float* __restrict__ E,
                                               float* __restrict__ ws,
                                               float* __restrict__ out) {
    int g = blockIdx.x * 256 + threadIdx.x;  // 256 blocks -> 65536 threads
    if (g == 0) ws[WS_LOSS] = 0.f;
    if (g < KEMB) {
        const float4* e4 = (const float4*)(E + (size_t)g * DIM);
        float s0 = 0.f, s1 = 0.f, s2 = 0.f, s3 = 0.f;
#pragma unroll
        for (int j = 0; j < 16; j++) {
            float4 v = e4[j];
            s0 = fmaf(v.x, v.x, s0); s1 = fmaf(v.y, v.y, s1);
            s2 = fmaf(v.z, v.z, s2); s3 = fmaf(v.w, v.w, s3);
        }
        ws[WS_ESQ + g] = (s0 + s1) + (s2 + s3);
    }
    {
        const float4* x4 = (const float4*)(x + (size_t)g * DIM);
        float s0 = 0.f, s1 = 0.f, s2 = 0.f, s3 = 0.f;
#pragma unroll
        for (int j = 0; j < 16; j++) {
            float4 v = x4[j];
            s0 = fmaf(v.x, v.x, s0); s1 = fmaf(v.y, v.y, s1);
            s2 = fmaf(v.z, v.z, s2); s3 = fmaf(v.w, v.w, s3);
        }
        out[OUT_NE + g] = (s0 + s1) + (s2 + s3);
    }
}

// K1: SGEMM-structured argmin. 512 blocks x 256 threads.
// Block: 128 rows x 2048 codes (16 passes of 128). Thread (tx=t&15, ty=t>>4)
// owns an 8x8 micro-tile. Register-prefetch double-staging: pass p+1's global
// E loads are issued right after pass p's stage, hidden under the 64-d FMA loop.
__global__ __launch_bounds__(256, 2) void k1_main(const float* __restrict__ x,
                                                  const float* __restrict__ E,
                                                  float* __restrict__ ws,
                                                  float* __restrict__ out) {
    __shared__ float sxT[64 * 128];   // 32 KB
    __shared__ float seT[64 * 128];   // 32 KB; reused as int sIdx[128] at the end

    const int t = threadIdx.x;
    const int b = blockIdx.x;
    const int tx = t & 15;
    const int ty = t >> 4;

    // x_sq for my 8 rows (scratch from k0; even offset -> float2 loads)
    float xsq[8];
    {
        const float2* xs2 = (const float2*)(out + OUT_NE + (size_t)b * 128 + ty * 8);
#pragma unroll
        for (int j = 0; j < 4; j++) {
            float2 v = xs2[j];
            xsq[2 * j] = v.x; xsq[2 * j + 1] = v.y;
        }
    }

    // ---- stage xT (once); lanes r-fast -> conflict-free LDS writes ----
    const int kl = t & 127;
    const int dchi = t >> 7;
    {
        const float4* x4 = (const float4*)x;
#pragma unroll
        for (int i = 0; i < 8; i++) {
            int dc = dchi + 2 * i;
            float4 v = x4[((size_t)b * 128 + kl) * 16 + dc];
            sxT[(4 * dc + 0) * 128 + kl] = v.x;
            sxT[(4 * dc + 1) * 128 + kl] = v.y;
            sxT[(4 * dc + 2) * 128 + kl] = v.z;
            sxT[(4 * dc + 3) * 128 + kl] = v.w;
        }
    }

    // eT staging geometry: code-chunk c (4 floats) -> float4-pos (c&1)*16 + (c>>1)
    const int c = kl >> 2;
    const int fo = (((c & 1) << 4) + (c >> 1)) * 4 + (kl & 3);
    const float4* e4 = (const float4*)E;

    float4 pv[8];
#pragma unroll
    for (int i = 0; i < 8; i++)
        pv[i] = e4[((size_t)kl) * 16 + (dchi + 2 * i)];   // pass 0 prefetch

    float best[8];
    int bidx[8];
#pragma unroll
    for (int rr = 0; rr < 8; rr++) { best[rr] = 3.4e38f; bidx[rr] = 0; }

    f32x4* __restrict__ encz = (f32x4*)(out + OUT_ENC);
    const int g = b * 256 + t;

    for (int pass = 0; pass < 16; pass++) {
        __syncthreads();   // prior compute done reading seT
        {
#pragma unroll
            for (int i = 0; i < 8; i++) {
                int dc = dchi + 2 * i;
                seT[(4 * dc + 0) * 128 + fo] = pv[i].x;
                seT[(4 * dc + 1) * 128 + fo] = pv[i].y;
                seT[(4 * dc + 2) * 128 + fo] = pv[i].z;
                seT[(4 * dc + 3) * 128 + fo] = pv[i].w;
            }
        }
        __syncthreads();

        // prefetch next pass's E chunk (drains under the FMA loop)
        if (pass < 15) {
#pragma unroll
            for (int i = 0; i < 8; i++)
                pv[i] = e4[((size_t)(pass + 1) * 128 + kl) * 16 + (dchi + 2 * i)];
        }

        // zero-fill slice of encodings (drains under the FMA loop)
        {
            f32x4 z = (f32x4)(0.f);
#pragma unroll
            for (int j = 0; j < 16; j++)
                __builtin_nontemporal_store(z, encz + (size_t)(pass * 16 + j) * 131072 + g);
        }

        // ---- 8x8 outer-product accumulation over d ----
        float acc[8][8];
#pragma unroll
        for (int rr = 0; rr < 8; rr++)
#pragma unroll
            for (int cc = 0; cc < 8; cc++) acc[rr][cc] = 0.f;

        const float* xb  = sxT + ty * 8;
        const float* ebA = seT + tx * 4;        // codes tx*8+0..3
        const float* ebB = seT + 64 + tx * 4;   // codes tx*8+4..7
#pragma unroll 2
        for (int d = 0; d < 64; d++) {
            f32x4 a0 = *(const f32x4*)(xb + d * 128);
            f32x4 a1 = *(const f32x4*)(xb + d * 128 + 4);
            f32x4 b0 = *(const f32x4*)(ebA + d * 128);
            f32x4 b1 = *(const f32x4*)(ebB + d * 128);
#pragma unroll
            for (int rr = 0; rr < 4; rr++) {
#pragma unroll
                for (int cc = 0; cc < 4; cc++) {
                    acc[rr][cc]         = fmaf(a0[rr], b0[cc], acc[rr][cc]);
                    acc[rr][cc + 4]     = fmaf(a0[rr], b1[cc], acc[rr][cc + 4]);
                    acc[rr + 4][cc]     = fmaf(a1[rr], b0[cc], acc[rr + 4][cc]);
                    acc[rr + 4][cc + 4] = fmaf(a1[rr], b1[cc], acc[rr + 4][cc + 4]);
                }
            }
        }

        // ---- fold distances into running argmin (k ascending -> first-min rule) ----
        const float4* esq4 = (const float4*)(ws + WS_ESQ + pass * 128 + tx * 8);
        float4 eq0 = esq4[0], eq1 = esq4[1];
        float eq[8] = {eq0.x, eq0.y, eq0.z, eq0.w, eq1.x, eq1.y, eq1.z, eq1.w};
        const int kb = pass * 128 + tx * 8;
#pragma unroll
        for (int rr = 0; rr < 8; rr++)
#pragma unroll
            for (int cc = 0; cc < 8; cc++) {
                float dist = fmaf(-2.f, acc[rr][cc], xsq[rr]) + eq[cc];
                if (dist < best[rr]) { best[rr] = dist; bidx[rr] = kb + cc; }
            }
    }

    // ---- cross-tx reduce: xor butterfly over the 16 lanes sharing rows ----
    __syncthreads();                       // seT reads done; reuse as sIdx
    int* sIdx = (int*)seT;
#pragma unroll
    for (int rr = 0; rr < 8; rr++) {
        float bd = best[rr]; int bi = bidx[rr];
#pragma unroll
        for (int m = 1; m < 16; m <<= 1) {
            float od = __shfl_xor(bd, m, 64);
            int   oi = __shfl_xor(bi, m, 64);
            if (od < bd || (od == bd && oi < bi)) { bd = od; bi = oi; }
        }
        if (tx == 0) sIdx[ty * 8 + rr] = bi;
    }
    __syncthreads();

    // ---- tail: idx write, quantized gather, loss ----
    if (t < 128) {
        const int row = b * 128 + t;
        const int bi = sIdx[t];
        ((int*)ws)[WS_IDX + row] = bi;
        const float4* ebb = (const float4*)(E + (size_t)bi * DIM);
        const float4* xr4 = (const float4*)(x + (size_t)row * DIM);
        float4* qo = (float4*)(out + OUT_Q + (size_t)row * DIM);
        float l0 = 0.f, l1 = 0.f, l2 = 0.f, l3 = 0.f;
#pragma unroll
        for (int j = 0; j < 16; j++) {
            float4 ev = ebb[j];
            float4 xv = xr4[j];
            qo[j] = ev;
            float d0 = ev.x - xv.x, d1 = ev.y - xv.y;
            float d2 = ev.z - xv.z, d3 = ev.w - xv.w;
            l0 = fmaf(d0, d0, l0); l1 = fmaf(d1, d1, l1);
            l2 = fmaf(d2, d2, l2); l3 = fmaf(d3, d3, l3);
        }
        float lsum = (l0 + l1) + (l2 + l3);
#pragma unroll
        for (int o = 32; o; o >>= 1) lsum += __shfl_down(lsum, o, 64);
        if ((t & 63) == 0) unsafeAtomicAdd(ws + WS_LOSS, lsum);
    }
}

// K2: one block per code k. Coalesced scan of idx; fused: count, dw, one-hot
// scatter. ~32 matches/block via LDS atomics; 8 waves/SIMD hides gather latency.
__global__ __launch_bounds__(256) void k2_dw(const int* __restrict__ idxp,
                                             const float* __restrict__ x,
                                             float* __restrict__ ws,
                                             float* __restrict__ out) {
    __shared__ float sdw[DIM];
    __shared__ unsigned int swc[4];
    const int t = threadIdx.x;
    const int k = blockIdx.x;

    if (t < DIM) sdw[t] = 0.f;
    __syncthreads();

    const int4* idx4 = (const int4*)idxp;
    float* __restrict__ enc = out + OUT_ENC;
    unsigned int cnt = 0;

    for (int j = 0; j < 64; j++) {
        int4 v = idx4[j * 256 + t];
        int rbase = (j * 256 + t) * 4;
#pragma unroll
        for (int cc = 0; cc < 4; cc++) {
            if ((&v.x)[cc] == k) {
                int row = rbase + cc;
                cnt++;
                enc[(size_t)row * KEMB + k] = 1.0f;
                const float4* xr4 = (const float4*)(x + (size_t)row * DIM);
#pragma unroll
                for (int j2 = 0; j2 < 16; j2++) {
                    float4 xv = xr4[j2];
                    atomicAdd(&sdw[4 * j2 + 0], xv.x);
                    atomicAdd(&sdw[4 * j2 + 1], xv.y);
                    atomicAdd(&sdw[4 * j2 + 2], xv.z);
                    atomicAdd(&sdw[4 * j2 + 3], xv.w);
                }
            }
        }
    }
#pragma unroll
    for (int o = 32; o; o >>= 1) cnt += __shfl_down(cnt, o, 64);
    if ((t & 63) == 0) swc[t >> 6] = cnt;
    __syncthreads();
    if (t < DIM) ws[WS_DW + (size_t)k * DIM + t] = sdw[t];
    if (t == 0)
        ((unsigned int*)ws)[WS_CNT + k] = swc[0] + swc[1] + swc[2] + swc[3];
}

// K3: cluster stats, loss, perplexity, scale for K4. One block of 256.
__global__ __launch_bounds__(256) void k3_stats(const float* __restrict__ cs_in,
                                                float* __restrict__ ws,
                                                float* __restrict__ out) {
    __shared__ float sred[8];
    __shared__ float s_n;
    int t = threadIdx.x;
    const unsigned int* cnt = ((const unsigned int*)ws) + WS_CNT;
    float* ncs_out = out + OUT_NCS;

    float ln = 0.f, lent = 0.f;
    float ncs_v[8];
#pragma unroll
    for (int j = 0; j < 8; j++) {
        int k = t + j * 256;
        float c = (float)cnt[k];
        float ncs = DECAYF * cs_in[k] + OMDF * c;
        ncs_out[k] = ncs;
        ncs_v[j] = ncs;
        ln += ncs;
        float p = c * (1.0f / 65536.0f);
        lent = fmaf(p, logf(p + 1e-10f), lent);
    }
#pragma unroll
    for (int o = 32; o; o >>= 1) {
        ln += __shfl_down(ln, o, 64);
        lent += __shfl_down(lent, o, 64);
    }
    if ((t & 63) == 0) { sred[t >> 6] = ln; sred[4 + (t >> 6)] = lent; }
    __syncthreads();
    if (t == 0) {
        float n = (sred[0] + sred[1]) + (sred[2] + sred[3]);
        float ent = (sred[4] + sred[5]) + (sred[6] + sred[7]);
        s_n = n;
        out[OUT_LOSS] = ws[WS_LOSS] * (1.0f / 4194304.0f);
        out[OUT_PERP] = expf(-ent);
    }
    __syncthreads();
    float n = s_n;
    float denom = n + (float)KEMB * EPSF;
#pragma unroll
    for (int j = 0; j < 8; j++) {
        int k = t + j * 256;
        float cs = (ncs_v[j] + EPSF) / denom * n;
        ws[WS_SCALE + k] = OMDF / cs;
    }
}

// K4: new_embedding = decay*E + dw * (0.01/cs). Overwrites the x_sq scratch.
__global__ __launch_bounds__(256) void k4_embed(const float* __restrict__ E,
                                                const float* __restrict__ ws,
                                                float* __restrict__ out) {
    int gq = blockIdx.x * 256 + threadIdx.x;  // 128 blocks -> 32768 float4-granules
    const float4* E4 = (const float4*)E;
    const float4* dw4 = (const float4*)(ws + WS_DW);
    float2* o2 = (float2*)(out + OUT_NE);
    int k = gq >> 4;
    float sc = ws[WS_SCALE + k];
    float4 e = E4[gq];
    float4 d = dw4[gq];
    float2 r0, r1;
    r0.x = fmaf(d.x, sc, DECAYF * e.x);
    r0.y = fmaf(d.y, sc, DECAYF * e.y);
    r1.x = fmaf(d.z, sc, DECAYF * e.z);
    r1.y = fmaf(d.w, sc, DECAYF * e.w);
    o2[2 * gq + 0] = r0;
    o2[2 * gq + 1] = r1;
}

extern "C" void kernel_launch(void* const* d_in, const int* in_sizes, int n_in,
                              void* d_out, int out_size, void* d_ws, size_t ws_size,
                              hipStream_t stream) {
    const float* x = (const float*)d_in[0];
    const float* E = (const float*)d_in[1];
    const float* cs = (const float*)d_in[2];
    float* out = (float*)d_out;
    float* ws = (float*)d_ws;

    hipLaunchKernelGGL(k0_prep, dim3(256), dim3(256), 0, stream, x, E, ws, out);
    hipLaunchKernelGGL(k1_main, dim3(512), dim3(256), 0, stream, x, E, ws, out);
    hipLaunchKernelGGL(k2_dw, dim3(2048), dim3(256), 0, stream,
                       ((const int*)ws) + WS_IDX, x, ws, out);
    hipLaunchKernelGGL(k3_stats, dim3(1), dim3(256), 0, stream, cs, ws, out);
    hipLaunchKernelGGL(k4_embed, dim3(128), dim3(256), 0, stream, E, ws, out);
}

// Round 5
// 654.473 us; speedup vs baseline: 2.3468x; 2.3468x over previous
//
#include <hip/hip_runtime.h>
#include <math.h>

#define NROWS 65536
#define KEMB  2048
#define DIM   64
#define DECAYF 0.99f
#define OMDF   0.01f
#define EPSF   1e-5f

// ---- ws layout (units of 4 bytes) ----
#define WS_DW    0         // 131072 floats (dw, fully written by k2d)
#define WS_CNT   131072    // 2048 uints   (counts; zeroed by k0, filled by k2a)
#define WS_LOSS  133120    // 1 float      (zeroed by k0)
#define WS_ESQ   133632    // 2048 floats  (e_sq)
#define WS_SCALE 135680    // 2048 floats  (0.01/cs', k2bs->k4)
#define WS_IDX   137728    // 65536 ints   (argmin indices)
#define WS_SORT  203264    // 65536 ints   (row ids sorted by code)
#define WS_START 268800    // 2049 uints   (segment starts)
#define WS_CUR   270852    // 2048 uints   (scatter cursors)

// ---- out layout (floats) ----
#define OUT_Q    0
#define OUT_ENC  4194304          // 65536*64
#define OUT_LOSS 138412032        // + 65536*2048
#define OUT_PERP 138412033
#define OUT_NE   138412034        // new_embedding; x_sq scratch k0->k1, overwritten by k4
#define OUT_NCS  138543106        // + 2048*64

typedef float f32x4 __attribute__((ext_vector_type(4)));

// K0: e_sq, x_sq, zero loss + counts
__global__ __launch_bounds__(256) void k0_prep(const float* __restrict__ x,
                                               const float* __restrict__ E,
                                               float* __restrict__ ws,
                                               float* __restrict__ out) {
    int g = blockIdx.x * 256 + threadIdx.x;  // 256 blocks -> 65536 threads
    if (g == 0) ws[WS_LOSS] = 0.f;
    if (g < KEMB) {
        ((unsigned int*)ws)[WS_CNT + g] = 0u;
        const float4* e4 = (const float4*)(E + (size_t)g * DIM);
        float s0 = 0.f, s1 = 0.f, s2 = 0.f, s3 = 0.f;
#pragma unroll
        for (int j = 0; j < 16; j++) {
            float4 v = e4[j];
            s0 = fmaf(v.x, v.x, s0); s1 = fmaf(v.y, v.y, s1);
            s2 = fmaf(v.z, v.z, s2); s3 = fmaf(v.w, v.w, s3);
        }
        ws[WS_ESQ + g] = (s0 + s1) + (s2 + s3);
    }
    {
        const float4* x4 = (const float4*)(x + (size_t)g * DIM);
        float s0 = 0.f, s1 = 0.f, s2 = 0.f, s3 = 0.f;
#pragma unroll
        for (int j = 0; j < 16; j++) {
            float4 v = x4[j];
            s0 = fmaf(v.x, v.x, s0); s1 = fmaf(v.y, v.y, s1);
            s2 = fmaf(v.z, v.z, s2); s3 = fmaf(v.w, v.w, s3);
        }
        out[OUT_NE + g] = (s0 + s1) + (s2 + s3);
    }
}

// K1: SGEMM-structured argmin (proven ~FMA-floor in R4). 512 blocks x 256 thr.
__global__ __launch_bounds__(256, 2) void k1_main(const float* __restrict__ x,
                                                  const float* __restrict__ E,
                                                  float* __restrict__ ws,
                                                  float* __restrict__ out) {
    __shared__ float sxT[64 * 128];   // 32 KB
    __shared__ float seT[64 * 128];   // 32 KB; reused as int sIdx[128] at the end

    const int t = threadIdx.x;
    const int b = blockIdx.x;
    const int tx = t & 15;
    const int ty = t >> 4;

    float xsq[8];
    {
        const float2* xs2 = (const float2*)(out + OUT_NE + (size_t)b * 128 + ty * 8);
#pragma unroll
        for (int j = 0; j < 4; j++) {
            float2 v = xs2[j];
            xsq[2 * j] = v.x; xsq[2 * j + 1] = v.y;
        }
    }

    const int kl = t & 127;
    const int dchi = t >> 7;
    {
        const float4* x4 = (const float4*)x;
#pragma unroll
        for (int i = 0; i < 8; i++) {
            int dc = dchi + 2 * i;
            float4 v = x4[((size_t)b * 128 + kl) * 16 + dc];
            sxT[(4 * dc + 0) * 128 + kl] = v.x;
            sxT[(4 * dc + 1) * 128 + kl] = v.y;
            sxT[(4 * dc + 2) * 128 + kl] = v.z;
            sxT[(4 * dc + 3) * 128 + kl] = v.w;
        }
    }

    const int c = kl >> 2;
    const int fo = (((c & 1) << 4) + (c >> 1)) * 4 + (kl & 3);
    const float4* e4 = (const float4*)E;

    float4 pv[8];
#pragma unroll
    for (int i = 0; i < 8; i++)
        pv[i] = e4[((size_t)kl) * 16 + (dchi + 2 * i)];   // pass 0 prefetch

    float best[8];
    int bidx[8];
#pragma unroll
    for (int rr = 0; rr < 8; rr++) { best[rr] = 3.4e38f; bidx[rr] = 0; }

    f32x4* __restrict__ encz = (f32x4*)(out + OUT_ENC);
    const int g = b * 256 + t;

    for (int pass = 0; pass < 16; pass++) {
        __syncthreads();
        {
#pragma unroll
            for (int i = 0; i < 8; i++) {
                int dc = dchi + 2 * i;
                seT[(4 * dc + 0) * 128 + fo] = pv[i].x;
                seT[(4 * dc + 1) * 128 + fo] = pv[i].y;
                seT[(4 * dc + 2) * 128 + fo] = pv[i].z;
                seT[(4 * dc + 3) * 128 + fo] = pv[i].w;
            }
        }
        __syncthreads();

        if (pass < 15) {
#pragma unroll
            for (int i = 0; i < 8; i++)
                pv[i] = e4[((size_t)(pass + 1) * 128 + kl) * 16 + (dchi + 2 * i)];
        }

        {
            f32x4 z = (f32x4)(0.f);
#pragma unroll
            for (int j = 0; j < 16; j++)
                __builtin_nontemporal_store(z, encz + (size_t)(pass * 16 + j) * 131072 + g);
        }

        float acc[8][8];
#pragma unroll
        for (int rr = 0; rr < 8; rr++)
#pragma unroll
            for (int cc = 0; cc < 8; cc++) acc[rr][cc] = 0.f;

        const float* xb  = sxT + ty * 8;
        const float* ebA = seT + tx * 4;
        const float* ebB = seT + 64 + tx * 4;
#pragma unroll 2
        for (int d = 0; d < 64; d++) {
            f32x4 a0 = *(const f32x4*)(xb + d * 128);
            f32x4 a1 = *(const f32x4*)(xb + d * 128 + 4);
            f32x4 b0 = *(const f32x4*)(ebA + d * 128);
            f32x4 b1 = *(const f32x4*)(ebB + d * 128);
#pragma unroll
            for (int rr = 0; rr < 4; rr++) {
#pragma unroll
                for (int cc = 0; cc < 4; cc++) {
                    acc[rr][cc]         = fmaf(a0[rr], b0[cc], acc[rr][cc]);
                    acc[rr][cc + 4]     = fmaf(a0[rr], b1[cc], acc[rr][cc + 4]);
                    acc[rr + 4][cc]     = fmaf(a1[rr], b0[cc], acc[rr + 4][cc]);
                    acc[rr + 4][cc + 4] = fmaf(a1[rr], b1[cc], acc[rr + 4][cc + 4]);
                }
            }
        }

        const float4* esq4 = (const float4*)(ws + WS_ESQ + pass * 128 + tx * 8);
        float4 eq0 = esq4[0], eq1 = esq4[1];
        float eq[8] = {eq0.x, eq0.y, eq0.z, eq0.w, eq1.x, eq1.y, eq1.z, eq1.w};
        const int kb = pass * 128 + tx * 8;
#pragma unroll
        for (int rr = 0; rr < 8; rr++)
#pragma unroll
            for (int cc = 0; cc < 8; cc++) {
                float dist = fmaf(-2.f, acc[rr][cc], xsq[rr]) + eq[cc];
                if (dist < best[rr]) { best[rr] = dist; bidx[rr] = kb + cc; }
            }
    }

    __syncthreads();
    int* sIdx = (int*)seT;
#pragma unroll
    for (int rr = 0; rr < 8; rr++) {
        float bd = best[rr]; int bi = bidx[rr];
#pragma unroll
        for (int m = 1; m < 16; m <<= 1) {
            float od = __shfl_xor(bd, m, 64);
            int   oi = __shfl_xor(bi, m, 64);
            if (od < bd || (od == bd && oi < bi)) { bd = od; bi = oi; }
        }
        if (tx == 0) sIdx[ty * 8 + rr] = bi;
    }
    __syncthreads();

    if (t < 128) {
        const int row = b * 128 + t;
        const int bi = sIdx[t];
        ((int*)ws)[WS_IDX + row] = bi;
        const float4* ebb = (const float4*)(E + (size_t)bi * DIM);
        const float4* xr4 = (const float4*)(x + (size_t)row * DIM);
        float4* qo = (float4*)(out + OUT_Q + (size_t)row * DIM);
        float l0 = 0.f, l1 = 0.f, l2 = 0.f, l3 = 0.f;
#pragma unroll
        for (int j = 0; j < 16; j++) {
            float4 ev = ebb[j];
            float4 xv = xr4[j];
            qo[j] = ev;
            float d0 = ev.x - xv.x, d1 = ev.y - xv.y;
            float d2 = ev.z - xv.z, d3 = ev.w - xv.w;
            l0 = fmaf(d0, d0, l0); l1 = fmaf(d1, d1, l1);
            l2 = fmaf(d2, d2, l2); l3 = fmaf(d3, d3, l3);
        }
        float lsum = (l0 + l1) + (l2 + l3);
#pragma unroll
        for (int o = 32; o; o >>= 1) lsum += __shfl_down(lsum, o, 64);
        if ((t & 63) == 0) unsafeAtomicAdd(ws + WS_LOSS, lsum);
    }
}

// K2a: histogram counts. 64 blocks; LDS pre-aggregation -> low-contention global adds.
__global__ __launch_bounds__(256) void k2a_hist(const int* __restrict__ idxp,
                                                float* __restrict__ ws) {
    __shared__ unsigned int hist[KEMB];
    const int t = threadIdx.x;
#pragma unroll
    for (int j = 0; j < 8; j++) hist[t + 256 * j] = 0u;
    __syncthreads();
    int4 v = ((const int4*)idxp)[blockIdx.x * 256 + t];
    atomicAdd(&hist[v.x], 1u);
    atomicAdd(&hist[v.y], 1u);
    atomicAdd(&hist[v.z], 1u);
    atomicAdd(&hist[v.w], 1u);
    __syncthreads();
    unsigned int* cnt = ((unsigned int*)ws) + WS_CNT;
#pragma unroll
    for (int j = 0; j < 8; j++) {
        unsigned int h = hist[t + 256 * j];
        if (h) atomicAdd(&cnt[t + 256 * j], h);
    }
}

// K2bs: prefix-sum of counts -> starts/cursor, fused with stats (loss scale,
// perplexity, new_cluster_size, K4 scale). One block of 256.
__global__ __launch_bounds__(256) void k2bs(const float* __restrict__ cs_in,
                                            float* __restrict__ ws,
                                            float* __restrict__ out) {
    __shared__ unsigned int sscan[256];
    __shared__ float sred[8];
    __shared__ float s_n;
    const int t = threadIdx.x;
    const unsigned int* cnt = ((const unsigned int*)ws) + WS_CNT;

    unsigned int c[8];
    unsigned int tot = 0;
#pragma unroll
    for (int j = 0; j < 8; j++) { c[j] = cnt[t * 8 + j]; tot += c[j]; }
    sscan[t] = tot;
    __syncthreads();
    for (int off = 1; off < 256; off <<= 1) {
        unsigned int v = (t >= off) ? sscan[t - off] : 0u;
        __syncthreads();
        sscan[t] += v;
        __syncthreads();
    }
    unsigned int run = sscan[t] - tot;
    unsigned int* starts = ((unsigned int*)ws) + WS_START;
    unsigned int* cur = ((unsigned int*)ws) + WS_CUR;
#pragma unroll
    for (int j = 0; j < 8; j++) {
        starts[t * 8 + j] = run;
        cur[t * 8 + j] = run;
        run += c[j];
    }
    if (t == 255) starts[KEMB] = run;

    // ---- stats ----
    float* ncs_out = out + OUT_NCS;
    float ln = 0.f, lent = 0.f;
    float ncs_v[8];
#pragma unroll
    for (int j = 0; j < 8; j++) {
        int k = t * 8 + j;
        float cf = (float)c[j];
        float ncs = DECAYF * cs_in[k] + OMDF * cf;
        ncs_out[k] = ncs;
        ncs_v[j] = ncs;
        ln += ncs;
        float p = cf * (1.0f / 65536.0f);
        lent = fmaf(p, logf(p + 1e-10f), lent);
    }
#pragma unroll
    for (int o = 32; o; o >>= 1) {
        ln += __shfl_down(ln, o, 64);
        lent += __shfl_down(lent, o, 64);
    }
    if ((t & 63) == 0) { sred[t >> 6] = ln; sred[4 + (t >> 6)] = lent; }
    __syncthreads();
    if (t == 0) {
        float n = (sred[0] + sred[1]) + (sred[2] + sred[3]);
        float ent = (sred[4] + sred[5]) + (sred[6] + sred[7]);
        s_n = n;
        out[OUT_LOSS] = ws[WS_LOSS] * (1.0f / 4194304.0f);
        out[OUT_PERP] = expf(-ent);
    }
    __syncthreads();
    float n = s_n;
    float denom = n + (float)KEMB * EPSF;
#pragma unroll
    for (int j = 0; j < 8; j++) {
        int k = t * 8 + j;
        float cs = (ncs_v[j] + EPSF) / denom * n;
        ws[WS_SCALE + k] = OMDF / cs;
    }
}

// K2c: scatter rows into code-sorted order + one-hot stores. 64 blocks.
__global__ __launch_bounds__(256) void k2c_scatter(const int* __restrict__ idxp,
                                                   float* __restrict__ ws,
                                                   float* __restrict__ out) {
    const int g = blockIdx.x * 256 + threadIdx.x;
    int4 v = ((const int4*)idxp)[g];
    unsigned int* cur = ((unsigned int*)ws) + WS_CUR;
    int* sorted = ((int*)ws) + WS_SORT;
    float* __restrict__ enc = out + OUT_ENC;
    const int row = 4 * g;
    unsigned int p0 = atomicAdd(&cur[v.x], 1u);
    unsigned int p1 = atomicAdd(&cur[v.y], 1u);
    unsigned int p2 = atomicAdd(&cur[v.z], 1u);
    unsigned int p3 = atomicAdd(&cur[v.w], 1u);
    sorted[p0] = row + 0;
    sorted[p1] = row + 1;
    sorted[p2] = row + 2;
    sorted[p3] = row + 3;
    enc[(size_t)(row + 0) * KEMB + v.x] = 1.0f;
    enc[(size_t)(row + 1) * KEMB + v.y] = 1.0f;
    enc[(size_t)(row + 2) * KEMB + v.z] = 1.0f;
    enc[(size_t)(row + 3) * KEMB + v.w] = 1.0f;
}

// K2d: per-code dense reduction. One wave per code (512 blocks x 4 waves);
// lane d sums x[row][d] over the code's segment -> fully coalesced, no atomics.
__global__ __launch_bounds__(256) void k2d_dw(const float* __restrict__ x,
                                              float* __restrict__ ws) {
    const int t = threadIdx.x;
    const int lane = t & 63;
    const int k = blockIdx.x * 4 + (t >> 6);
    const unsigned int* starts = ((const unsigned int*)ws) + WS_START;
    const int* sorted = ((const int*)ws) + WS_SORT;
    const unsigned int s = starts[k], e = starts[k + 1];
    float acc = 0.f;
    for (unsigned int i = s; i < e; i++) {
        int row = sorted[i];
        acc += x[(size_t)row * DIM + lane];
    }
    ws[WS_DW + (size_t)k * DIM + lane] = acc;
}

// K4: new_embedding = decay*E + dw * (0.01/cs). Overwrites the x_sq scratch.
__global__ __launch_bounds__(256) void k4_embed(const float* __restrict__ E,
                                                const float* __restrict__ ws,
                                                float* __restrict__ out) {
    int gq = blockIdx.x * 256 + threadIdx.x;  // 128 blocks -> 32768 float4-granules
    const float4* E4 = (const float4*)E;
    const float4* dw4 = (const float4*)(ws + WS_DW);
    float2* o2 = (float2*)(out + OUT_NE);
    int k = gq >> 4;
    float sc = ws[WS_SCALE + k];
    float4 e = E4[gq];
    float4 d = dw4[gq];
    float2 r0, r1;
    r0.x = fmaf(d.x, sc, DECAYF * e.x);
    r0.y = fmaf(d.y, sc, DECAYF * e.y);
    r1.x = fmaf(d.z, sc, DECAYF * e.z);
    r1.y = fmaf(d.w, sc, DECAYF * e.w);
    o2[2 * gq + 0] = r0;
    o2[2 * gq + 1] = r1;
}

extern "C" void kernel_launch(void* const* d_in, const int* in_sizes, int n_in,
                              void* d_out, int out_size, void* d_ws, size_t ws_size,
                              hipStream_t stream) {
    const float* x = (const float*)d_in[0];
    const float* E = (const float*)d_in[1];
    const float* cs = (const float*)d_in[2];
    float* out = (float*)d_out;
    float* ws = (float*)d_ws;
    const int* idxp = ((const int*)ws) + WS_IDX;

    hipLaunchKernelGGL(k0_prep, dim3(256), dim3(256), 0, stream, x, E, ws, out);
    hipLaunchKernelGGL(k1_main, dim3(512), dim3(256), 0, stream, x, E, ws, out);
    hipLaunchKernelGGL(k2a_hist, dim3(64), dim3(256), 0, stream, idxp, ws);
    hipLaunchKernelGGL(k2bs, dim3(1), dim3(256), 0, stream, cs, ws, out);
    hipLaunchKernelGGL(k2c_scatter, dim3(64), dim3(256), 0, stream, idxp, ws, out);
    hipLaunchKernelGGL(k2d_dw, dim3(512), dim3(256), 0, stream, x, ws);
    hipLaunchKernelGGL(k4_embed, dim3(128), dim3(256), 0, stream, E, ws, out);
}

// Round 6
// 294.427 us; speedup vs baseline: 5.2166x; 2.2229x over previous
//
#include <hip/hip_runtime.h>
#include <math.h>

#define NROWS 65536
#define KEMB  2048
#define DIM   64
#define DECAYF 0.99f
#define OMDF   0.01f
#define EPSF   1e-5f

// ---- ws layout (units of 4 bytes) ----
#define WS_DW    0         // 131072 floats (zeroed by k0, accumulated by k2d)
#define WS_CNT   131072    // 2048 uints   (zeroed by k0, filled by k1 tail)
#define WS_LOSS  133120    // 1 float      (zeroed by k0)
#define WS_ESQ   133632    // 2048 floats  (e_sq)
#define WS_SCALE 135680    // 2048 floats  (0.01/cs', k2bs->k4)
#define WS_IDX   137728    // 65536 ints   (argmin indices)
#define WS_SORT  203264    // 65536 ints   (row ids sorted by code)
#define WS_START 268800    // 2049 uints   (segment starts)
#define WS_CUR   270852    // 2048 uints   (scatter cursors)

// ---- out layout (floats) ----
#define OUT_Q    0
#define OUT_ENC  4194304          // 65536*64
#define OUT_LOSS 138412032        // + 65536*2048
#define OUT_PERP 138412033
#define OUT_NE   138412034        // new_embedding; x_sq scratch k0->k1, overwritten by k4
#define OUT_NCS  138543106        // + 2048*64

typedef float f32x4 __attribute__((ext_vector_type(4)));

// K0: e_sq, x_sq, zero loss + counts + dw
__global__ __launch_bounds__(256) void k0_prep(const float* __restrict__ x,
                                               const float* __restrict__ E,
                                               float* __restrict__ ws,
                                               float* __restrict__ out) {
    int g = blockIdx.x * 256 + threadIdx.x;  // 256 blocks -> 65536 threads
    if (g == 0) ws[WS_LOSS] = 0.f;
    if (g < 32768) {
        float4 z = make_float4(0.f, 0.f, 0.f, 0.f);
        ((float4*)(ws + WS_DW))[g] = z;
    }
    if (g < KEMB) {
        ((unsigned int*)ws)[WS_CNT + g] = 0u;
        const float4* e4 = (const float4*)(E + (size_t)g * DIM);
        float s0 = 0.f, s1 = 0.f, s2 = 0.f, s3 = 0.f;
#pragma unroll
        for (int j = 0; j < 16; j++) {
            float4 v = e4[j];
            s0 = fmaf(v.x, v.x, s0); s1 = fmaf(v.y, v.y, s1);
            s2 = fmaf(v.z, v.z, s2); s3 = fmaf(v.w, v.w, s3);
        }
        ws[WS_ESQ + g] = (s0 + s1) + (s2 + s3);
    }
    {
        const float4* x4 = (const float4*)(x + (size_t)g * DIM);
        float s0 = 0.f, s1 = 0.f, s2 = 0.f, s3 = 0.f;
#pragma unroll
        for (int j = 0; j < 16; j++) {
            float4 v = x4[j];
            s0 = fmaf(v.x, v.x, s0); s1 = fmaf(v.y, v.y, s1);
            s2 = fmaf(v.z, v.z, s2); s3 = fmaf(v.w, v.w, s3);
        }
        out[OUT_NE + g] = (s0 + s1) + (s2 + s3);
    }
}

// K1: SGEMM-structured argmin (at f32-FMA floor). 512 blocks x 256 thr.
// Tail now also bumps the per-code count (hidden under the FMA wall).
__global__ __launch_bounds__(256, 2) void k1_main(const float* __restrict__ x,
                                                  const float* __restrict__ E,
                                                  float* __restrict__ ws,
                                                  float* __restrict__ out) {
    __shared__ float sxT[64 * 128];   // 32 KB
    __shared__ float seT[64 * 128];   // 32 KB; reused as int sIdx[128] at the end

    const int t = threadIdx.x;
    const int b = blockIdx.x;
    const int tx = t & 15;
    const int ty = t >> 4;

    float xsq[8];
    {
        const float2* xs2 = (const float2*)(out + OUT_NE + (size_t)b * 128 + ty * 8);
#pragma unroll
        for (int j = 0; j < 4; j++) {
            float2 v = xs2[j];
            xsq[2 * j] = v.x; xsq[2 * j + 1] = v.y;
        }
    }

    const int kl = t & 127;
    const int dchi = t >> 7;
    {
        const float4* x4 = (const float4*)x;
#pragma unroll
        for (int i = 0; i < 8; i++) {
            int dc = dchi + 2 * i;
            float4 v = x4[((size_t)b * 128 + kl) * 16 + dc];
            sxT[(4 * dc + 0) * 128 + kl] = v.x;
            sxT[(4 * dc + 1) * 128 + kl] = v.y;
            sxT[(4 * dc + 2) * 128 + kl] = v.z;
            sxT[(4 * dc + 3) * 128 + kl] = v.w;
        }
    }

    const int c = kl >> 2;
    const int fo = (((c & 1) << 4) + (c >> 1)) * 4 + (kl & 3);
    const float4* e4 = (const float4*)E;

    float4 pv[8];
#pragma unroll
    for (int i = 0; i < 8; i++)
        pv[i] = e4[((size_t)kl) * 16 + (dchi + 2 * i)];   // pass 0 prefetch

    float best[8];
    int bidx[8];
#pragma unroll
    for (int rr = 0; rr < 8; rr++) { best[rr] = 3.4e38f; bidx[rr] = 0; }

    f32x4* __restrict__ encz = (f32x4*)(out + OUT_ENC);
    const int g = b * 256 + t;

    for (int pass = 0; pass < 16; pass++) {
        __syncthreads();
        {
#pragma unroll
            for (int i = 0; i < 8; i++) {
                int dc = dchi + 2 * i;
                seT[(4 * dc + 0) * 128 + fo] = pv[i].x;
                seT[(4 * dc + 1) * 128 + fo] = pv[i].y;
                seT[(4 * dc + 2) * 128 + fo] = pv[i].z;
                seT[(4 * dc + 3) * 128 + fo] = pv[i].w;
            }
        }
        __syncthreads();

        if (pass < 15) {
#pragma unroll
            for (int i = 0; i < 8; i++)
                pv[i] = e4[((size_t)(pass + 1) * 128 + kl) * 16 + (dchi + 2 * i)];
        }

        {
            f32x4 z = (f32x4)(0.f);
#pragma unroll
            for (int j = 0; j < 16; j++)
                __builtin_nontemporal_store(z, encz + (size_t)(pass * 16 + j) * 131072 + g);
        }

        float acc[8][8];
#pragma unroll
        for (int rr = 0; rr < 8; rr++)
#pragma unroll
            for (int cc = 0; cc < 8; cc++) acc[rr][cc] = 0.f;

        const float* xb  = sxT + ty * 8;
        const float* ebA = seT + tx * 4;
        const float* ebB = seT + 64 + tx * 4;
#pragma unroll 2
        for (int d = 0; d < 64; d++) {
            f32x4 a0 = *(const f32x4*)(xb + d * 128);
            f32x4 a1 = *(const f32x4*)(xb + d * 128 + 4);
            f32x4 b0 = *(const f32x4*)(ebA + d * 128);
            f32x4 b1 = *(const f32x4*)(ebB + d * 128);
#pragma unroll
            for (int rr = 0; rr < 4; rr++) {
#pragma unroll
                for (int cc = 0; cc < 4; cc++) {
                    acc[rr][cc]         = fmaf(a0[rr], b0[cc], acc[rr][cc]);
                    acc[rr][cc + 4]     = fmaf(a0[rr], b1[cc], acc[rr][cc + 4]);
                    acc[rr + 4][cc]     = fmaf(a1[rr], b0[cc], acc[rr + 4][cc]);
                    acc[rr + 4][cc + 4] = fmaf(a1[rr], b1[cc], acc[rr + 4][cc + 4]);
                }
            }
        }

        const float4* esq4 = (const float4*)(ws + WS_ESQ + pass * 128 + tx * 8);
        float4 eq0 = esq4[0], eq1 = esq4[1];
        float eq[8] = {eq0.x, eq0.y, eq0.z, eq0.w, eq1.x, eq1.y, eq1.z, eq1.w};
        const int kb = pass * 128 + tx * 8;
#pragma unroll
        for (int rr = 0; rr < 8; rr++)
#pragma unroll
            for (int cc = 0; cc < 8; cc++) {
                float dist = fmaf(-2.f, acc[rr][cc], xsq[rr]) + eq[cc];
                if (dist < best[rr]) { best[rr] = dist; bidx[rr] = kb + cc; }
            }
    }

    __syncthreads();
    int* sIdx = (int*)seT;
#pragma unroll
    for (int rr = 0; rr < 8; rr++) {
        float bd = best[rr]; int bi = bidx[rr];
#pragma unroll
        for (int m = 1; m < 16; m <<= 1) {
            float od = __shfl_xor(bd, m, 64);
            int   oi = __shfl_xor(bi, m, 64);
            if (od < bd || (od == bd && oi < bi)) { bd = od; bi = oi; }
        }
        if (tx == 0) sIdx[ty * 8 + rr] = bi;
    }
    __syncthreads();

    if (t < 128) {
        const int row = b * 128 + t;
        const int bi = sIdx[t];
        ((int*)ws)[WS_IDX + row] = bi;
        atomicAdd(((unsigned int*)ws) + WS_CNT + bi, 1u);
        const float4* ebb = (const float4*)(E + (size_t)bi * DIM);
        const float4* xr4 = (const float4*)(x + (size_t)row * DIM);
        float4* qo = (float4*)(out + OUT_Q + (size_t)row * DIM);
        float l0 = 0.f, l1 = 0.f, l2 = 0.f, l3 = 0.f;
#pragma unroll
        for (int j = 0; j < 16; j++) {
            float4 ev = ebb[j];
            float4 xv = xr4[j];
            qo[j] = ev;
            float d0 = ev.x - xv.x, d1 = ev.y - xv.y;
            float d2 = ev.z - xv.z, d3 = ev.w - xv.w;
            l0 = fmaf(d0, d0, l0); l1 = fmaf(d1, d1, l1);
            l2 = fmaf(d2, d2, l2); l3 = fmaf(d3, d3, l3);
        }
        float lsum = (l0 + l1) + (l2 + l3);
#pragma unroll
        for (int o = 32; o; o >>= 1) lsum += __shfl_down(lsum, o, 64);
        if ((t & 63) == 0) unsafeAtomicAdd(ws + WS_LOSS, lsum);
    }
}

// K2bs: prefix-sum of counts -> starts/cursor, fused with stats. One block.
__global__ __launch_bounds__(256) void k2bs(const float* __restrict__ cs_in,
                                            float* __restrict__ ws,
                                            float* __restrict__ out) {
    __shared__ unsigned int sscan[256];
    __shared__ float sred[8];
    __shared__ float s_n;
    const int t = threadIdx.x;
    const unsigned int* cnt = ((const unsigned int*)ws) + WS_CNT;

    unsigned int c[8];
    unsigned int tot = 0;
#pragma unroll
    for (int j = 0; j < 8; j++) { c[j] = cnt[t * 8 + j]; tot += c[j]; }
    sscan[t] = tot;
    __syncthreads();
    for (int off = 1; off < 256; off <<= 1) {
        unsigned int v = (t >= off) ? sscan[t - off] : 0u;
        __syncthreads();
        sscan[t] += v;
        __syncthreads();
    }
    unsigned int run = sscan[t] - tot;
    unsigned int* starts = ((unsigned int*)ws) + WS_START;
    unsigned int* cur = ((unsigned int*)ws) + WS_CUR;
#pragma unroll
    for (int j = 0; j < 8; j++) {
        starts[t * 8 + j] = run;
        cur[t * 8 + j] = run;
        run += c[j];
    }
    if (t == 255) starts[KEMB] = run;

    float* ncs_out = out + OUT_NCS;
    float ln = 0.f, lent = 0.f;
    float ncs_v[8];
#pragma unroll
    for (int j = 0; j < 8; j++) {
        int k = t * 8 + j;
        float cf = (float)c[j];
        float ncs = DECAYF * cs_in[k] + OMDF * cf;
        ncs_out[k] = ncs;
        ncs_v[j] = ncs;
        ln += ncs;
        float p = cf * (1.0f / 65536.0f);
        lent = fmaf(p, logf(p + 1e-10f), lent);
    }
#pragma unroll
    for (int o = 32; o; o >>= 1) {
        ln += __shfl_down(ln, o, 64);
        lent += __shfl_down(lent, o, 64);
    }
    if ((t & 63) == 0) { sred[t >> 6] = ln; sred[4 + (t >> 6)] = lent; }
    __syncthreads();
    if (t == 0) {
        float n = (sred[0] + sred[1]) + (sred[2] + sred[3]);
        float ent = (sred[4] + sred[5]) + (sred[6] + sred[7]);
        s_n = n;
        out[OUT_LOSS] = ws[WS_LOSS] * (1.0f / 4194304.0f);
        out[OUT_PERP] = expf(-ent);
    }
    __syncthreads();
    float n = s_n;
    float denom = n + (float)KEMB * EPSF;
#pragma unroll
    for (int j = 0; j < 8; j++) {
        int k = t * 8 + j;
        float cs = (ncs_v[j] + EPSF) / denom * n;
        ws[WS_SCALE + k] = OMDF / cs;
    }
}

// K2c: scatter rows into code-sorted order + one-hot stores. 64 blocks.
__global__ __launch_bounds__(256) void k2c_scatter(const int* __restrict__ idxp,
                                                   float* __restrict__ ws,
                                                   float* __restrict__ out) {
    const int g = blockIdx.x * 256 + threadIdx.x;
    int4 v = ((const int4*)idxp)[g];
    unsigned int* cur = ((unsigned int*)ws) + WS_CUR;
    int* sorted = ((int*)ws) + WS_SORT;
    float* __restrict__ enc = out + OUT_ENC;
    const int row = 4 * g;
    unsigned int p0 = atomicAdd(&cur[v.x], 1u);
    unsigned int p1 = atomicAdd(&cur[v.y], 1u);
    unsigned int p2 = atomicAdd(&cur[v.z], 1u);
    unsigned int p3 = atomicAdd(&cur[v.w], 1u);
    sorted[p0] = row + 0;
    sorted[p1] = row + 1;
    sorted[p2] = row + 2;
    sorted[p3] = row + 3;
    enc[(size_t)(row + 0) * KEMB + v.x] = 1.0f;
    enc[(size_t)(row + 1) * KEMB + v.y] = 1.0f;
    enc[(size_t)(row + 2) * KEMB + v.z] = 1.0f;
    enc[(size_t)(row + 3) * KEMB + v.w] = 1.0f;
}

// K2d: dw reduction over TILES of the sorted row array (load-balanced: every
// wave does exactly 64 rows regardless of cluster-size skew). One boundary
// flush (float atomic) per distinct code per tile; branches are wave-uniform.
__global__ __launch_bounds__(256) void k2d_dw(const float* __restrict__ x,
                                              const int* __restrict__ idxp,
                                              float* __restrict__ ws) {
    const int t = threadIdx.x;
    const int lane = t & 63;
    const int w = blockIdx.x * 4 + (t >> 6);   // 256 blocks -> 1024 waves
    const int base = w * 64;
    const int* sorted = ((const int*)ws) + WS_SORT;

    int rid = sorted[base + lane];   // my tile's row ids, one per lane
    int code_l = idxp[rid];          // their codes

    float acc = 0.f;
    int cur = __shfl(code_l, 0, 64);
#pragma unroll 8
    for (int i = 0; i < 64; i++) {
        int row = __shfl(rid, i, 64);
        int code = __shfl(code_l, i, 64);
        if (code != cur) {           // wave-uniform branch (rare)
            unsafeAtomicAdd(ws + WS_DW + (size_t)cur * DIM + lane, acc);
            acc = 0.f;
            cur = code;
        }
        acc += x[(size_t)row * DIM + lane];
    }
    unsafeAtomicAdd(ws + WS_DW + (size_t)cur * DIM + lane, acc);
}

// K4: new_embedding = decay*E + dw * (0.01/cs). Overwrites the x_sq scratch.
__global__ __launch_bounds__(256) void k4_embed(const float* __restrict__ E,
                                                const float* __restrict__ ws,
                                                float* __restrict__ out) {
    int gq = blockIdx.x * 256 + threadIdx.x;  // 128 blocks -> 32768 float4-granules
    const float4* E4 = (const float4*)E;
    const float4* dw4 = (const float4*)(ws + WS_DW);
    float2* o2 = (float2*)(out + OUT_NE);
    int k = gq >> 4;
    float sc = ws[WS_SCALE + k];
    float4 e = E4[gq];
    float4 d = dw4[gq];
    float2 r0, r1;
    r0.x = fmaf(d.x, sc, DECAYF * e.x);
    r0.y = fmaf(d.y, sc, DECAYF * e.y);
    r1.x = fmaf(d.z, sc, DECAYF * e.z);
    r1.y = fmaf(d.w, sc, DECAYF * e.w);
    o2[2 * gq + 0] = r0;
    o2[2 * gq + 1] = r1;
}

extern "C" void kernel_launch(void* const* d_in, const int* in_sizes, int n_in,
                              void* d_out, int out_size, void* d_ws, size_t ws_size,
                              hipStream_t stream) {
    const float* x = (const float*)d_in[0];
    const float* E = (const float*)d_in[1];
    const float* cs = (const float*)d_in[2];
    float* out = (float*)d_out;
    float* ws = (float*)d_ws;
    const int* idxp = ((const int*)ws) + WS_IDX;

    hipLaunchKernelGGL(k0_prep, dim3(256), dim3(256), 0, stream, x, E, ws, out);
    hipLaunchKernelGGL(k1_main, dim3(512), dim3(256), 0, stream, x, E, ws, out);
    hipLaunchKernelGGL(k2bs, dim3(1), dim3(256), 0, stream, cs, ws, out);
    hipLaunchKernelGGL(k2c_scatter, dim3(64), dim3(256), 0, stream, idxp, ws, out);
    hipLaunchKernelGGL(k2d_dw, dim3(256), dim3(256), 0, stream, x, idxp, ws);
    hipLaunchKernelGGL(k4_embed, dim3(128), dim3(256), 0, stream, E, ws, out);
}